// Round 1
// baseline (709.306 us; speedup 1.0000x reference)
//
#include <hip/hip_runtime.h>
#include <cstdint>
#include <cstddef>

#define DIM    512
#define HEADS  8
#define DHEAD  64
#define NSEQ   256
#define BATCH  64
#define NROWS  (BATCH * NSEQ)   // 16384
#define HB     (HEADS * BATCH)  // 512

__device__ __forceinline__ float sigmoidf_(float x) { return 1.0f / (1.0f + expf(-x)); }

// ---------------------------------------------------------------------------
// Kernel 1: per-row LayerNorm stats (mean, rstd). One wave (64 lanes) per row.
// ---------------------------------------------------------------------------
__global__ __launch_bounds__(256)
void ln_stats_kernel(const float* __restrict__ x, float2* __restrict__ out)
{
    const int wid = threadIdx.x >> 6, lane = threadIdx.x & 63;
    const int row = blockIdx.x * 4 + wid;
    const float* xr = x + (size_t)row * DIM;
    float v[8];
    float s = 0.f;
#pragma unroll
    for (int i = 0; i < 8; ++i) { v[i] = xr[lane + 64 * i]; s += v[i]; }
#pragma unroll
    for (int o = 32; o > 0; o >>= 1) s += __shfl_xor(s, o, 64);
    const float mu = s * (1.f / DIM);
    float sq = 0.f;
#pragma unroll
    for (int i = 0; i < 8; ++i) { float d = v[i] - mu; sq += d * d; }
#pragma unroll
    for (int o = 32; o > 0; o >>= 1) sq += __shfl_xor(sq, o, 64);
    if (lane == 0) out[row] = make_float2(mu, rsqrtf(sq * (1.f / DIM) + 1e-5f));
}

// ---------------------------------------------------------------------------
// Kernel 2/6: fp32 GEMM  C[M,512] = A'[M,512] @ W[512,512] (+bias)
// A' = LN(A) if LN template flag. Tile 128x64, 256 threads, 8x4 per thread.
// ---------------------------------------------------------------------------
template <bool LN>
__global__ __launch_bounds__(256)
void gemm512_kernel(const float* __restrict__ A, const float2* __restrict__ murstd,
                    const float* __restrict__ gam, const float* __restrict__ bet,
                    const float* __restrict__ W, const float* __restrict__ bias,
                    float* __restrict__ C)
{
    __shared__ float As[16][128];   // transposed: As[k][row]
    __shared__ float Bs[16][64];
    const int r0 = blockIdx.x * 128, c0 = blockIdx.y * 64;
    const int t = threadIdx.x, tx = t & 15, ty = t >> 4;
    float acc[8][4] = {};
    for (int k0 = 0; k0 < DIM; k0 += 16) {
#pragma unroll
        for (int i = 0; i < 2; ++i) {
            int idx = t + 256 * i;          // 0..511 over 128 rows x 4 float4
            int row = idx >> 2, kq = (idx & 3) << 2;
            float4 xv = *(const float4*)(A + (size_t)(r0 + row) * DIM + k0 + kq);
            if (LN) {
                float2 ms = murstd[r0 + row];
                xv.x = (xv.x - ms.x) * ms.y * gam[k0 + kq + 0] + bet[k0 + kq + 0];
                xv.y = (xv.y - ms.x) * ms.y * gam[k0 + kq + 1] + bet[k0 + kq + 1];
                xv.z = (xv.z - ms.x) * ms.y * gam[k0 + kq + 2] + bet[k0 + kq + 2];
                xv.w = (xv.w - ms.x) * ms.y * gam[k0 + kq + 3] + bet[k0 + kq + 3];
            }
            As[kq + 0][row] = xv.x; As[kq + 1][row] = xv.y;
            As[kq + 2][row] = xv.z; As[kq + 3][row] = xv.w;
        }
        {
            int kk = t >> 4, cc = (t & 15) << 2;
            *(float4*)&Bs[kk][cc] = *(const float4*)(W + (size_t)(k0 + kk) * DIM + c0 + cc);
        }
        __syncthreads();
#pragma unroll
        for (int kk = 0; kk < 16; ++kk) {
            float4 b4 = *(float4*)&Bs[kk][tx << 2];
            float4 a0 = *(float4*)&As[kk][ty << 3];
            float4 a1 = *(float4*)&As[kk][(ty << 3) + 4];
            float a[8] = {a0.x, a0.y, a0.z, a0.w, a1.x, a1.y, a1.z, a1.w};
            float b[4] = {b4.x, b4.y, b4.z, b4.w};
#pragma unroll
            for (int j = 0; j < 8; ++j)
#pragma unroll
                for (int c = 0; c < 4; ++c) acc[j][c] += a[j] * b[c];
        }
        __syncthreads();
    }
#pragma unroll
    for (int j = 0; j < 8; ++j) {
        int r = r0 + (ty << 3) + j;
        float4 v = make_float4(acc[j][0], acc[j][1], acc[j][2], acc[j][3]);
        if (!LN) {
            int c = c0 + (tx << 2);
            v.x += bias[c]; v.y += bias[c + 1]; v.z += bias[c + 2]; v.w += bias[c + 3];
        }
        *(float4*)(C + (size_t)r * DIM + c0 + (tx << 2)) = v;
    }
}

// ---------------------------------------------------------------------------
// Kernel 3: per-(h,b) stats for q (tns=0) and k (tns=1):
//   row L2 norms, per-dim sigma -> v_hb, centered Gram -> c_hb
// One block per (hb, tns). Streams 4 chunks of 64 rows through LDS.
// ---------------------------------------------------------------------------
__global__ __launch_bounds__(256)
void stats_kernel(const float* __restrict__ F, float* __restrict__ norms,
                  float2* __restrict__ vc)
{
    __shared__ float tile[64][68];   // pad 68: 16B-aligned rows, conflict-free
    __shared__ float red[4][64];
    __shared__ float mu[64];
    __shared__ float redsc[64];
    __shared__ float wred[4][2];
    const int hb = blockIdx.x, tns = blockIdx.y;
    const int h = hb >> 6, b = hb & 63;
    const float* Fb = F + (size_t)tns * NROWS * DIM + (size_t)b * NSEQ * DIM + h * DHEAD;
    const int t = threadIdx.x;
    const int col = t & 63, grp = t >> 6;
    const int tx = t & 15, ty = t >> 4;

    // ---- pass 1: column sums (for mu) + row norms ----
    float colsum = 0.f;
    for (int c = 0; c < 4; ++c) {
#pragma unroll
        for (int i = 0; i < 4; ++i) {
            int idx = t + 256 * i;
            int r = idx >> 4, d4 = (idx & 15) << 2;
            *(float4*)&tile[r][d4] = *(const float4*)(Fb + (size_t)(c * 64 + r) * DIM + d4);
        }
        __syncthreads();
        float cs = 0.f;
#pragma unroll
        for (int kk = 0; kk < 16; ++kk) cs += tile[grp + 4 * kk][col];
        colsum += cs;
        float ns = 0.f;
#pragma unroll
        for (int d = 0; d < 16; ++d) { float x = tile[col][grp * 16 + d]; ns += x * x; }
        red[grp][col] = ns;
        __syncthreads();
        if (t < 64)
            norms[((size_t)tns * HB + hb) * NSEQ + c * 64 + t] =
                sqrtf(red[0][t] + red[1][t] + red[2][t] + red[3][t]);
        __syncthreads();
    }
    red[grp][col] = colsum;
    __syncthreads();
    if (t < 64) mu[t] = (red[0][t] + red[1][t] + red[2][t] + red[3][t]) * (1.f / NSEQ);
    __syncthreads();

    // ---- pass 2: centered column sumsq (sigma) + Gram (cov energy) ----
    float gr[4][4] = {};
    float colsq = 0.f;
    for (int c = 0; c < 4; ++c) {
#pragma unroll
        for (int i = 0; i < 4; ++i) {
            int idx = t + 256 * i;
            int r = idx >> 4, d4 = (idx & 15) << 2;
            float4 v = *(const float4*)(Fb + (size_t)(c * 64 + r) * DIM + d4);
            v.x -= mu[d4]; v.y -= mu[d4 + 1]; v.z -= mu[d4 + 2]; v.w -= mu[d4 + 3];
            *(float4*)&tile[r][d4] = v;
        }
        __syncthreads();
        float cs = 0.f;
#pragma unroll
        for (int kk = 0; kk < 16; ++kk) { float x = tile[grp + 4 * kk][col]; cs += x * x; }
        colsq += cs;
#pragma unroll
        for (int n = 0; n < 64; ++n) {
            float4 a4 = *(float4*)&tile[n][ty << 2];
            float4 b4 = *(float4*)&tile[n][tx << 2];
            float a[4] = {a4.x, a4.y, a4.z, a4.w}, bb[4] = {b4.x, b4.y, b4.z, b4.w};
#pragma unroll
            for (int i = 0; i < 4; ++i)
#pragma unroll
                for (int j = 0; j < 4; ++j) gr[i][j] += a[i] * bb[j];
        }
        __syncthreads();
    }
    red[grp][col] = colsq;
    __syncthreads();
    if (t < 64) {
        float var = (red[0][t] + red[1][t] + red[2][t] + red[3][t]) * (1.f / (NSEQ - 1));
        float sig = sqrtf(var + 1e-8f);
        redsc[t] = fmaxf(1.0f - sig, 0.f);   // GAMMA = 1
    }
    float t2 = 0.f, d2 = 0.f;
#pragma unroll
    for (int i = 0; i < 4; ++i)
#pragma unroll
        for (int j = 0; j < 4; ++j) t2 += gr[i][j] * gr[i][j];
    if (tx == ty) {
#pragma unroll
        for (int i = 0; i < 4; ++i) d2 += gr[i][i] * gr[i][i];
    }
#pragma unroll
    for (int o = 32; o > 0; o >>= 1) {
        t2 += __shfl_xor(t2, o, 64);
        d2 += __shfl_xor(d2, o, 64);
    }
    if ((t & 63) == 0) { wred[t >> 6][0] = t2; wred[t >> 6][1] = d2; }
    __syncthreads();
    if (t == 0) {
        float T = wred[0][0] + wred[1][0] + wred[2][0] + wred[3][0];
        float D = wred[0][1] + wred[1][1] + wred[2][1] + wred[3][1];
        float vs = 0.f;
        for (int i = 0; i < 64; ++i) vs += redsc[i];
        float vv = vs * (1.f / 64.f);
        float cc = (T - D) * (1.f / ((float)(NSEQ - 1) * (float)(NSEQ - 1) * (float)DHEAD));
        vc[(size_t)tns * HB + hb] = make_float2(vv, cc);
    }
}

// ---------------------------------------------------------------------------
// Kernel 4: chunk-combine -> s_hb = cov_w*Cq_c*Ck_c + var_w*Vq_c*Vk_c
// ---------------------------------------------------------------------------
__global__ void combine_kernel(const float2* __restrict__ vc, const float* __restrict__ cov_logit,
                               const float* __restrict__ var_logit, float* __restrict__ s_out)
{
    int hb = threadIdx.x + blockIdx.x * blockDim.x;
    if (hb >= HB) return;
    int base = hb & ~7;
    float vq = 0, cq = 0, vk = 0, ck = 0;
#pragma unroll
    for (int m = 0; m < 8; ++m) {
        float2 a = vc[base + m];      vq += a.x; cq += a.y;
        float2 b = vc[HB + base + m]; vk += b.x; ck += b.y;
    }
    float cw = sigmoidf_(*cov_logit), vw = sigmoidf_(*var_logit);
    // (sum/8)*(sum/8) = sum*sum/64
    s_out[hb] = (cw * cq * ck + vw * vq * vk) * (1.f / 64.f);
}

// ---------------------------------------------------------------------------
// Kernel 5: attention per (h,b):
//   M = khat^T f_v  (64x64), sumv = sum_n f_v[n]
//   O[n] = cos_w * qhat[n] @ M + s_hb * sumv      -> G[b,n,h*64+:]
// ---------------------------------------------------------------------------
__global__ __launch_bounds__(256)
void attn_kernel(const float* __restrict__ F, const float* __restrict__ norms,
                 const float* __restrict__ s_arr, const float* __restrict__ cov_logit,
                 const float* __restrict__ var_logit, float* __restrict__ G)
{
    __shared__ float kh[64][68];
    __shared__ float fv[64][68];
    __shared__ float Ms[64][68];
    __shared__ float sv[64];
    __shared__ float red[4][64];
    const int hb = blockIdx.x, h = hb >> 6, b = hb & 63;
    const float* Fq = F + (size_t)b * NSEQ * DIM + h * DHEAD;
    const float* Fk = Fq + (size_t)NROWS * DIM;
    const float* Fv = Fk + (size_t)NROWS * DIM;
    const int t = threadIdx.x, tx = t & 15, ty = t >> 4, col = t & 63, grp = t >> 6;

    float m_acc[4][4] = {};
    float svp = 0.f;
    for (int c = 0; c < 4; ++c) {
#pragma unroll
        for (int i = 0; i < 4; ++i) {
            int idx = t + 256 * i;
            int r = idx >> 4, d4 = (idx & 15) << 2;
            float invn = 1.0f / norms[((size_t)1 * HB + hb) * NSEQ + c * 64 + r];
            float4 kv = *(const float4*)(Fk + (size_t)(c * 64 + r) * DIM + d4);
            kv.x *= invn; kv.y *= invn; kv.z *= invn; kv.w *= invn;
            *(float4*)&kh[r][d4] = kv;
            *(float4*)&fv[r][d4] = *(const float4*)(Fv + (size_t)(c * 64 + r) * DIM + d4);
        }
        __syncthreads();
        float cs = 0.f;
#pragma unroll
        for (int kk = 0; kk < 16; ++kk) cs += fv[grp + 4 * kk][col];
        svp += cs;
#pragma unroll
        for (int n = 0; n < 64; ++n) {
            float4 a4 = *(float4*)&kh[n][ty << 2];
            float4 b4 = *(float4*)&fv[n][tx << 2];
            float a[4] = {a4.x, a4.y, a4.z, a4.w}, bb[4] = {b4.x, b4.y, b4.z, b4.w};
#pragma unroll
            for (int i = 0; i < 4; ++i)
#pragma unroll
                for (int j = 0; j < 4; ++j) m_acc[i][j] += a[i] * bb[j];
        }
        __syncthreads();
    }
    red[grp][col] = svp;
    __syncthreads();
    if (t < 64) sv[t] = red[0][t] + red[1][t] + red[2][t] + red[3][t];
#pragma unroll
    for (int i = 0; i < 4; ++i)
#pragma unroll
        for (int j = 0; j < 4; ++j) Ms[(ty << 2) + i][(tx << 2) + j] = m_acc[i][j];
    __syncthreads();

    const float cw = sigmoidf_(*cov_logit), vw = sigmoidf_(*var_logit);
    const float cosw = 1.f - cw - vw;
    const float s = s_arr[hb];
    float qv[64];
    {
        float invq = 1.0f / norms[((size_t)0 * HB + hb) * NSEQ + t];
#pragma unroll
        for (int d4 = 0; d4 < 64; d4 += 4) {
            float4 v = *(const float4*)(Fq + (size_t)t * DIM + d4);
            qv[d4] = v.x * invq; qv[d4 + 1] = v.y * invq;
            qv[d4 + 2] = v.z * invq; qv[d4 + 3] = v.w * invq;
        }
    }
    float* Grow = G + (size_t)(b * NSEQ + t) * DIM + h * DHEAD;
#pragma unroll 1
    for (int jg = 0; jg < 64; jg += 8) {
        float o[8] = {};
#pragma unroll
        for (int i = 0; i < 64; ++i) {
            float qi = qv[i];
            float4 m0 = *(float4*)&Ms[i][jg];
            float4 m1 = *(float4*)&Ms[i][jg + 4];
            o[0] += qi * m0.x; o[1] += qi * m0.y; o[2] += qi * m0.z; o[3] += qi * m0.w;
            o[4] += qi * m1.x; o[5] += qi * m1.y; o[6] += qi * m1.z; o[7] += qi * m1.w;
        }
        float4 o0 = make_float4(cosw * o[0] + s * sv[jg + 0], cosw * o[1] + s * sv[jg + 1],
                                cosw * o[2] + s * sv[jg + 2], cosw * o[3] + s * sv[jg + 3]);
        float4 o1 = make_float4(cosw * o[4] + s * sv[jg + 4], cosw * o[5] + s * sv[jg + 5],
                                cosw * o[6] + s * sv[jg + 6], cosw * o[7] + s * sv[jg + 7]);
        *(float4*)(Grow + jg) = o0;
        *(float4*)(Grow + jg + 4) = o1;
    }
}

// ---------------------------------------------------------------------------
extern "C" void kernel_launch(void* const* d_in, const int* in_sizes, int n_in,
                              void* d_out, int out_size, void* d_ws, size_t ws_size,
                              hipStream_t stream)
{
    const float* q         = (const float*)d_in[0];
    const float* k         = (const float*)d_in[1];
    const float* v         = (const float*)d_in[2];
    const float* ln_g      = (const float*)d_in[3];
    const float* ln_b      = (const float*)d_in[4];
    const float* W_in      = (const float*)d_in[5];
    const float* W_out     = (const float*)d_in[6];
    const float* b_out     = (const float*)d_in[7];
    const float* cov_logit = (const float*)d_in[8];
    const float* var_logit = (const float*)d_in[9];
    float* out = (float*)d_out;
    float* ws  = (float*)d_ws;

    // workspace layout (floats)
    float2* rowstats = (float2*)ws;                               // 3*NROWS float2
    float*  Fbuf     = ws + (size_t)3 * NROWS * 2;                // 3*NROWS*DIM
    float*  norms    = Fbuf + (size_t)3 * NROWS * DIM;            // 2*HB*NSEQ
    float2* vc       = (float2*)(norms + (size_t)2 * HB * NSEQ);  // 2*HB float2
    float*  s_arr    = (float*)(vc + 2 * HB);                     // HB
    float*  Gbuf     = s_arr + HB;                                // NROWS*DIM

    const float* in3[3] = {q, k, v};
    for (int tns = 0; tns < 3; ++tns)
        ln_stats_kernel<<<dim3(NROWS / 4), 256, 0, stream>>>(in3[tns],
                                                             rowstats + (size_t)tns * NROWS);
    for (int tns = 0; tns < 3; ++tns)
        gemm512_kernel<true><<<dim3(NROWS / 128, DIM / 64), 256, 0, stream>>>(
            in3[tns], rowstats + (size_t)tns * NROWS, ln_g, ln_b, W_in, nullptr,
            Fbuf + (size_t)tns * NROWS * DIM);

    stats_kernel<<<dim3(HB, 2), 256, 0, stream>>>(Fbuf, norms, vc);
    combine_kernel<<<dim3(1), 512, 0, stream>>>(vc, cov_logit, var_logit, s_arr);
    attn_kernel<<<dim3(HB), 256, 0, stream>>>(Fbuf, norms, s_arr, cov_logit, var_logit, Gbuf);
    gemm512_kernel<false><<<dim3(NROWS / 128, DIM / 64), 256, 0, stream>>>(
        Gbuf, nullptr, nullptr, nullptr, W_out, b_out, out);
}

// Round 2
// 320.806 us; speedup vs baseline: 2.2110x; 2.2110x over previous
//
#include <hip/hip_runtime.h>
#include <cstdint>
#include <cstddef>

#define DIM    512
#define HEADS  8
#define DHEAD  64
#define NSEQ   256
#define BATCH  64
#define NROWS  (BATCH * NSEQ)   // 16384
#define HB     (HEADS * BATCH)  // 512

typedef unsigned short u16;
typedef __bf16 bf16x8 __attribute__((ext_vector_type(8)));
typedef float  f32x4  __attribute__((ext_vector_type(4)));

__device__ __forceinline__ float sigmoidf_(float x) { return 1.0f / (1.0f + expf(-x)); }

__device__ __forceinline__ u16 f2bf(float f) {
    union { float f; unsigned u; } a; a.f = f;
    return (u16)((a.u + 0x7fffu + ((a.u >> 16) & 1u)) >> 16);   // RNE
}

__device__ __forceinline__ void gload16(const void* g, void* l) {
    __builtin_amdgcn_global_load_lds((const __attribute__((address_space(1))) void*)g,
                                     (__attribute__((address_space(3))) void*)l, 16, 0, 0);
}

// ---------------------------------------------------------------------------
// Kernel 1: fused LayerNorm + bf16 cast. One wave per row; lane owns 8 contig.
// ---------------------------------------------------------------------------
__global__ __launch_bounds__(256)
void ln_cast_kernel(const float* __restrict__ x, const float* __restrict__ gam,
                    const float* __restrict__ bet, u16* __restrict__ out)
{
    const int wid = threadIdx.x >> 6, lane = threadIdx.x & 63;
    const int row = blockIdx.x * 4 + wid;
    const float* xr = x + (size_t)row * DIM;
    float4 a = *(const float4*)(xr + lane * 8);
    float4 b = *(const float4*)(xr + lane * 8 + 4);
    float v[8] = {a.x, a.y, a.z, a.w, b.x, b.y, b.z, b.w};
    float s = 0.f;
#pragma unroll
    for (int i = 0; i < 8; ++i) s += v[i];
#pragma unroll
    for (int o = 32; o > 0; o >>= 1) s += __shfl_xor(s, o, 64);
    const float mu = s * (1.f / DIM);
    float sq = 0.f;
#pragma unroll
    for (int i = 0; i < 8; ++i) { float d = v[i] - mu; sq += d * d; }
#pragma unroll
    for (int o = 32; o > 0; o >>= 1) sq += __shfl_xor(sq, o, 64);
    const float rstd = rsqrtf(sq * (1.f / DIM) + 1e-5f);
    float4 g0 = *(const float4*)(gam + lane * 8), g1 = *(const float4*)(gam + lane * 8 + 4);
    float4 b0 = *(const float4*)(bet + lane * 8), b1 = *(const float4*)(bet + lane * 8 + 4);
    float gv[8] = {g0.x, g0.y, g0.z, g0.w, g1.x, g1.y, g1.z, g1.w};
    float bv[8] = {b0.x, b0.y, b0.z, b0.w, b1.x, b1.y, b1.z, b1.w};
    union { u16 h[8]; uint4 u; } o16;
#pragma unroll
    for (int i = 0; i < 8; ++i) o16.h[i] = f2bf((v[i] - mu) * rstd * gv[i] + bv[i]);
    *(uint4*)(out + (size_t)row * DIM + lane * 8) = o16.u;
}

// ---------------------------------------------------------------------------
// Kernel 2: W [K,N] fp32 -> WT [N,K] bf16 (B^T layout for MFMA B fragments)
// ---------------------------------------------------------------------------
__global__ __launch_bounds__(256)
void transpose_cast_kernel(const float* __restrict__ W, u16* __restrict__ WT)
{
    __shared__ float tile[64][65];
    const int t = threadIdx.x;
    const int bx = blockIdx.x * 64, by = blockIdx.y * 64;
#pragma unroll
    for (int i = 0; i < 16; ++i) {
        int idx = i * 256 + t, r = idx >> 6, c = idx & 63;
        tile[r][c] = W[(size_t)(by + r) * DIM + bx + c];
    }
    __syncthreads();
#pragma unroll
    for (int i = 0; i < 16; ++i) {
        int idx = i * 256 + t, r = idx >> 6, c = idx & 63;
        WT[(size_t)(bx + r) * DIM + by + c] = f2bf(tile[c][r]);
    }
}

// ---------------------------------------------------------------------------
// Kernel 3/7: bf16 MFMA GEMM  C[M,512] = A[M,512] @ BT[512,512]^T (+bias)
// m97 structure: 128x128 tile, 4 waves, 4x4 16x16x32 accs, global_load_lds.
// ---------------------------------------------------------------------------
template <bool BIAS>
__global__ __launch_bounds__(256)
void mfma_gemm_kernel(const u16* __restrict__ A, const u16* __restrict__ BT,
                      const float* __restrict__ bias, float* __restrict__ C)
{
    __shared__ u16 As[128 * 32];
    __shared__ u16 Bs[128 * 32];
    const int t = threadIdx.x, lane = t & 63, w = t >> 6;
    const int wr = w >> 1, wc = w & 1;
    const int r0 = blockIdx.x * 128, c0 = blockIdx.y * 128;
    const int cl = lane & 15, q = lane >> 4;

    f32x4 acc[4][4];
#pragma unroll
    for (int i = 0; i < 4; ++i)
#pragma unroll
        for (int j = 0; j < 4; ++j) acc[i][j] = (f32x4){0.f, 0.f, 0.f, 0.f};

    for (int k0 = 0; k0 < DIM; k0 += 32) {
#pragma unroll
        for (int i = 0; i < 2; ++i) {
            int idx = i * 256 + t;               // 0..511: row=idx>>2, 16B chunk=idx&3
            int row = idx >> 2, ch = idx & 3;
            gload16(A  + (size_t)(r0 + row) * DIM + k0 + ch * 8, As + idx * 8);
            gload16(BT + (size_t)(c0 + row) * DIM + k0 + ch * 8, Bs + idx * 8);
        }
        __syncthreads();
        bf16x8 af[4], bfr[4];
#pragma unroll
        for (int mi = 0; mi < 4; ++mi)
            af[mi] = *(const bf16x8*)(As + (wr * 64 + mi * 16 + cl) * 32 + q * 8);
#pragma unroll
        for (int ni = 0; ni < 4; ++ni)
            bfr[ni] = *(const bf16x8*)(Bs + (wc * 64 + ni * 16 + cl) * 32 + q * 8);
#pragma unroll
        for (int mi = 0; mi < 4; ++mi)
#pragma unroll
            for (int ni = 0; ni < 4; ++ni)
                acc[mi][ni] = __builtin_amdgcn_mfma_f32_16x16x32_bf16(af[mi], bfr[ni],
                                                                      acc[mi][ni], 0, 0, 0);
        __syncthreads();
    }
#pragma unroll
    for (int mi = 0; mi < 4; ++mi) {
#pragma unroll
        for (int ni = 0; ni < 4; ++ni) {
            int col = c0 + wc * 64 + ni * 16 + cl;
            float bv = BIAS ? bias[col] : 0.f;
#pragma unroll
            for (int r = 0; r < 4; ++r) {
                int row = r0 + wr * 64 + mi * 16 + q * 4 + r;
                C[(size_t)row * DIM + col] = acc[mi][ni][r] + bv;
            }
        }
    }
}

// ---------------------------------------------------------------------------
// Kernel 4: per-(h,b) stats for q (tns=0) and k (tns=1) [unchanged, fp32 F]
// ---------------------------------------------------------------------------
__global__ __launch_bounds__(256)
void stats_kernel(const float* __restrict__ F, float* __restrict__ norms,
                  float2* __restrict__ vc)
{
    __shared__ float tile[64][68];
    __shared__ float red[4][64];
    __shared__ float mu[64];
    __shared__ float redsc[64];
    __shared__ float wred[4][2];
    const int hb = blockIdx.x, tns = blockIdx.y;
    const int h = hb >> 6, b = hb & 63;
    const float* Fb = F + (size_t)tns * NROWS * DIM + (size_t)b * NSEQ * DIM + h * DHEAD;
    const int t = threadIdx.x;
    const int col = t & 63, grp = t >> 6;
    const int tx = t & 15, ty = t >> 4;

    float colsum = 0.f;
    for (int c = 0; c < 4; ++c) {
#pragma unroll
        for (int i = 0; i < 4; ++i) {
            int idx = t + 256 * i;
            int r = idx >> 4, d4 = (idx & 15) << 2;
            *(float4*)&tile[r][d4] = *(const float4*)(Fb + (size_t)(c * 64 + r) * DIM + d4);
        }
        __syncthreads();
        float cs = 0.f;
#pragma unroll
        for (int kk = 0; kk < 16; ++kk) cs += tile[grp + 4 * kk][col];
        colsum += cs;
        float ns = 0.f;
#pragma unroll
        for (int d = 0; d < 16; ++d) { float x = tile[col][grp * 16 + d]; ns += x * x; }
        red[grp][col] = ns;
        __syncthreads();
        if (t < 64)
            norms[((size_t)tns * HB + hb) * NSEQ + c * 64 + t] =
                sqrtf(red[0][t] + red[1][t] + red[2][t] + red[3][t]);
        __syncthreads();
    }
    red[grp][col] = colsum;
    __syncthreads();
    if (t < 64) mu[t] = (red[0][t] + red[1][t] + red[2][t] + red[3][t]) * (1.f / NSEQ);
    __syncthreads();

    float gr[4][4] = {};
    float colsq = 0.f;
    for (int c = 0; c < 4; ++c) {
#pragma unroll
        for (int i = 0; i < 4; ++i) {
            int idx = t + 256 * i;
            int r = idx >> 4, d4 = (idx & 15) << 2;
            float4 v = *(const float4*)(Fb + (size_t)(c * 64 + r) * DIM + d4);
            v.x -= mu[d4]; v.y -= mu[d4 + 1]; v.z -= mu[d4 + 2]; v.w -= mu[d4 + 3];
            *(float4*)&tile[r][d4] = v;
        }
        __syncthreads();
        float cs = 0.f;
#pragma unroll
        for (int kk = 0; kk < 16; ++kk) { float x = tile[grp + 4 * kk][col]; cs += x * x; }
        colsq += cs;
#pragma unroll
        for (int n = 0; n < 64; ++n) {
            float4 a4 = *(float4*)&tile[n][ty << 2];
            float4 b4 = *(float4*)&tile[n][tx << 2];
            float a[4] = {a4.x, a4.y, a4.z, a4.w}, bb[4] = {b4.x, b4.y, b4.z, b4.w};
#pragma unroll
            for (int i = 0; i < 4; ++i)
#pragma unroll
                for (int j = 0; j < 4; ++j) gr[i][j] += a[i] * bb[j];
        }
        __syncthreads();
    }
    red[grp][col] = colsq;
    __syncthreads();
    if (t < 64) {
        float var = (red[0][t] + red[1][t] + red[2][t] + red[3][t]) * (1.f / (NSEQ - 1));
        float sig = sqrtf(var + 1e-8f);
        redsc[t] = fmaxf(1.0f - sig, 0.f);
    }
    float t2 = 0.f, d2 = 0.f;
#pragma unroll
    for (int i = 0; i < 4; ++i)
#pragma unroll
        for (int j = 0; j < 4; ++j) t2 += gr[i][j] * gr[i][j];
    if (tx == ty) {
#pragma unroll
        for (int i = 0; i < 4; ++i) d2 += gr[i][i] * gr[i][i];
    }
#pragma unroll
    for (int o = 32; o > 0; o >>= 1) {
        t2 += __shfl_xor(t2, o, 64);
        d2 += __shfl_xor(d2, o, 64);
    }
    if ((t & 63) == 0) { wred[t >> 6][0] = t2; wred[t >> 6][1] = d2; }
    __syncthreads();
    if (t == 0) {
        float T = wred[0][0] + wred[1][0] + wred[2][0] + wred[3][0];
        float D = wred[0][1] + wred[1][1] + wred[2][1] + wred[3][1];
        float vs = 0.f;
        for (int i = 0; i < 64; ++i) vs += redsc[i];
        float vv = vs * (1.f / 64.f);
        float cc = (T - D) * (1.f / ((float)(NSEQ - 1) * (float)(NSEQ - 1) * (float)DHEAD));
        vc[(size_t)tns * HB + hb] = make_float2(vv, cc);
    }
}

// ---------------------------------------------------------------------------
// Kernel 5: chunk-combine [unchanged]
// ---------------------------------------------------------------------------
__global__ void combine_kernel(const float2* __restrict__ vc, const float* __restrict__ cov_logit,
                               const float* __restrict__ var_logit, float* __restrict__ s_out)
{
    int hb = threadIdx.x + blockIdx.x * blockDim.x;
    if (hb >= HB) return;
    int base = hb & ~7;
    float vq = 0, cq = 0, vk = 0, ck = 0;
#pragma unroll
    for (int m = 0; m < 8; ++m) {
        float2 a = vc[base + m];      vq += a.x; cq += a.y;
        float2 b = vc[HB + base + m]; vk += b.x; ck += b.y;
    }
    float cw = sigmoidf_(*cov_logit), vw = sigmoidf_(*var_logit);
    s_out[hb] = (cw * cq * ck + vw * vq * vk) * (1.f / 64.f);
}

// ---------------------------------------------------------------------------
// Kernel 6: attention per (h,b); now writes bf16 G for the MFMA out-GEMM.
// ---------------------------------------------------------------------------
__global__ __launch_bounds__(256)
void attn_kernel(const float* __restrict__ F, const float* __restrict__ norms,
                 const float* __restrict__ s_arr, const float* __restrict__ cov_logit,
                 const float* __restrict__ var_logit, u16* __restrict__ G)
{
    __shared__ float kh[64][68];
    __shared__ float fv[64][68];
    __shared__ float Ms[64][68];
    __shared__ float sv[64];
    __shared__ float red[4][64];
    const int hb = blockIdx.x, h = hb >> 6, b = hb & 63;
    const float* Fq = F + (size_t)b * NSEQ * DIM + h * DHEAD;
    const float* Fk = Fq + (size_t)NROWS * DIM;
    const float* Fv = Fk + (size_t)NROWS * DIM;
    const int t = threadIdx.x, tx = t & 15, ty = t >> 4, col = t & 63, grp = t >> 6;

    float m_acc[4][4] = {};
    float svp = 0.f;
    for (int c = 0; c < 4; ++c) {
#pragma unroll
        for (int i = 0; i < 4; ++i) {
            int idx = t + 256 * i;
            int r = idx >> 4, d4 = (idx & 15) << 2;
            float invn = 1.0f / norms[((size_t)1 * HB + hb) * NSEQ + c * 64 + r];
            float4 kv = *(const float4*)(Fk + (size_t)(c * 64 + r) * DIM + d4);
            kv.x *= invn; kv.y *= invn; kv.z *= invn; kv.w *= invn;
            *(float4*)&kh[r][d4] = kv;
            *(float4*)&fv[r][d4] = *(const float4*)(Fv + (size_t)(c * 64 + r) * DIM + d4);
        }
        __syncthreads();
        float cs = 0.f;
#pragma unroll
        for (int kk = 0; kk < 16; ++kk) cs += fv[grp + 4 * kk][col];
        svp += cs;
#pragma unroll
        for (int n = 0; n < 64; ++n) {
            float4 a4 = *(float4*)&kh[n][ty << 2];
            float4 b4 = *(float4*)&fv[n][tx << 2];
            float a[4] = {a4.x, a4.y, a4.z, a4.w}, bb[4] = {b4.x, b4.y, b4.z, b4.w};
#pragma unroll
            for (int i = 0; i < 4; ++i)
#pragma unroll
                for (int j = 0; j < 4; ++j) m_acc[i][j] += a[i] * bb[j];
        }
        __syncthreads();
    }
    red[grp][col] = svp;
    __syncthreads();
    if (t < 64) sv[t] = red[0][t] + red[1][t] + red[2][t] + red[3][t];
#pragma unroll
    for (int i = 0; i < 4; ++i)
#pragma unroll
        for (int j = 0; j < 4; ++j) Ms[(ty << 2) + i][(tx << 2) + j] = m_acc[i][j];
    __syncthreads();

    const float cw = sigmoidf_(*cov_logit), vw = sigmoidf_(*var_logit);
    const float cosw = 1.f - cw - vw;
    const float s = s_arr[hb];
    float qv[64];
    {
        float invq = 1.0f / norms[((size_t)0 * HB + hb) * NSEQ + t];
#pragma unroll
        for (int d4 = 0; d4 < 64; d4 += 4) {
            float4 v = *(const float4*)(Fq + (size_t)t * DIM + d4);
            qv[d4] = v.x * invq; qv[d4 + 1] = v.y * invq;
            qv[d4 + 2] = v.z * invq; qv[d4 + 3] = v.w * invq;
        }
    }
    u16* Grow = G + (size_t)(b * NSEQ + t) * DIM + h * DHEAD;
#pragma unroll 1
    for (int jg = 0; jg < 64; jg += 8) {
        float o[8] = {};
#pragma unroll
        for (int i = 0; i < 64; ++i) {
            float qi = qv[i];
            float4 m0 = *(float4*)&Ms[i][jg];
            float4 m1 = *(float4*)&Ms[i][jg + 4];
            o[0] += qi * m0.x; o[1] += qi * m0.y; o[2] += qi * m0.z; o[3] += qi * m0.w;
            o[4] += qi * m1.x; o[5] += qi * m1.y; o[6] += qi * m1.z; o[7] += qi * m1.w;
        }
        union { u16 h[8]; uint4 u; } o16;
#pragma unroll
        for (int j = 0; j < 8; ++j) o16.h[j] = f2bf(cosw * o[j] + s * sv[jg + j]);
        *(uint4*)(Grow + jg) = o16.u;
    }
}

// ---------------------------------------------------------------------------
extern "C" void kernel_launch(void* const* d_in, const int* in_sizes, int n_in,
                              void* d_out, int out_size, void* d_ws, size_t ws_size,
                              hipStream_t stream)
{
    const float* q         = (const float*)d_in[0];
    const float* k         = (const float*)d_in[1];
    const float* v         = (const float*)d_in[2];
    const float* ln_g      = (const float*)d_in[3];
    const float* ln_b      = (const float*)d_in[4];
    const float* W_in      = (const float*)d_in[5];
    const float* W_out     = (const float*)d_in[6];
    const float* b_out     = (const float*)d_in[7];
    const float* cov_logit = (const float*)d_in[8];
    const float* var_logit = (const float*)d_in[9];
    float* out = (float*)d_out;

    // workspace layout (bytes): Abf(16.78M, reused as Gbf) | WT(1M) | Fbuf(100.7M)
    //                           | norms(1M) | vc(8K) | s_arr(2K)   total ~119.5 MB
    char* base = (char*)d_ws;
    u16*    Abf   = (u16*)base;
    u16*    WT    = (u16*)(base + (size_t)16777216);
    float*  Fbuf  = (float*)(base + (size_t)16777216 + 1048576);
    float*  norms = (float*)(base + (size_t)16777216 + 1048576 + 100663296);
    float2* vc    = (float2*)((char*)norms + 1048576);
    float*  s_arr = (float*)((char*)vc + 8192);

    transpose_cast_kernel<<<dim3(8, 8), 256, 0, stream>>>(W_in, WT);
    transpose_cast_kernel<<<dim3(8, 8), 256, 0, stream>>>(W_out, WT + 512 * 512);

    const float* in3[3] = {q, k, v};
    for (int tns = 0; tns < 3; ++tns) {
        ln_cast_kernel<<<dim3(NROWS / 4), 256, 0, stream>>>(in3[tns], ln_g, ln_b, Abf);
        mfma_gemm_kernel<false><<<dim3(NROWS / 128, 4), 256, 0, stream>>>(
            Abf, WT, nullptr, Fbuf + (size_t)tns * NROWS * DIM);
    }

    stats_kernel<<<dim3(HB, 2), 256, 0, stream>>>(Fbuf, norms, vc);
    combine_kernel<<<dim3(1), 512, 0, stream>>>(vc, cov_logit, var_logit, s_arr);
    attn_kernel<<<dim3(HB), 256, 0, stream>>>(Fbuf, norms, s_arr, cov_logit, var_logit, Abf);
    mfma_gemm_kernel<true><<<dim3(NROWS / 128, 4), 256, 0, stream>>>(
        Abf, WT + 512 * 512, b_out, out);
}

// Round 3
// 256.094 us; speedup vs baseline: 2.7697x; 1.2527x over previous
//
#include <hip/hip_runtime.h>
#include <cstdint>
#include <cstddef>

#define DIM    512
#define HEADS  8
#define DHEAD  64
#define NSEQ   256
#define BATCH  64
#define NROWS  (BATCH * NSEQ)   // 16384
#define HB     (HEADS * BATCH)  // 512

typedef unsigned short u16;
typedef __bf16 bf16x8 __attribute__((ext_vector_type(8)));
typedef float  f32x4  __attribute__((ext_vector_type(4)));

__device__ __forceinline__ float sigmoidf_(float x) { return 1.0f / (1.0f + expf(-x)); }

__device__ __forceinline__ u16 f2bf(float f) {
    union { float f; unsigned u; } a; a.f = f;
    return (u16)((a.u + 0x7fffu + ((a.u >> 16) & 1u)) >> 16);   // RNE
}

__device__ __forceinline__ void gload16(const void* g, void* l) {
    __builtin_amdgcn_global_load_lds((const __attribute__((address_space(1))) void*)g,
                                     (__attribute__((address_space(3))) void*)l, 16, 0, 0);
}

// ---------------------------------------------------------------------------
// Kernel 1: fused LayerNorm + bf16 cast. One wave per row.
// ---------------------------------------------------------------------------
__global__ __launch_bounds__(256)
void ln_cast_kernel(const float* __restrict__ x, const float* __restrict__ gam,
                    const float* __restrict__ bet, u16* __restrict__ out)
{
    const int wid = threadIdx.x >> 6, lane = threadIdx.x & 63;
    const int row = blockIdx.x * 4 + wid;
    const float* xr = x + (size_t)row * DIM;
    float4 a = *(const float4*)(xr + lane * 8);
    float4 b = *(const float4*)(xr + lane * 8 + 4);
    float v[8] = {a.x, a.y, a.z, a.w, b.x, b.y, b.z, b.w};
    float s = 0.f;
#pragma unroll
    for (int i = 0; i < 8; ++i) s += v[i];
#pragma unroll
    for (int o = 32; o > 0; o >>= 1) s += __shfl_xor(s, o, 64);
    const float mu = s * (1.f / DIM);
    float sq = 0.f;
#pragma unroll
    for (int i = 0; i < 8; ++i) { float d = v[i] - mu; sq += d * d; }
#pragma unroll
    for (int o = 32; o > 0; o >>= 1) sq += __shfl_xor(sq, o, 64);
    const float rstd = rsqrtf(sq * (1.f / DIM) + 1e-5f);
    float4 g0 = *(const float4*)(gam + lane * 8), g1 = *(const float4*)(gam + lane * 8 + 4);
    float4 b0 = *(const float4*)(bet + lane * 8), b1 = *(const float4*)(bet + lane * 8 + 4);
    float gv[8] = {g0.x, g0.y, g0.z, g0.w, g1.x, g1.y, g1.z, g1.w};
    float bv[8] = {b0.x, b0.y, b0.z, b0.w, b1.x, b1.y, b1.z, b1.w};
    union { u16 h[8]; uint4 u; } o16;
#pragma unroll
    for (int i = 0; i < 8; ++i) o16.h[i] = f2bf((v[i] - mu) * rstd * gv[i] + bv[i]);
    *(uint4*)(out + (size_t)row * DIM + lane * 8) = o16.u;
}

// ---------------------------------------------------------------------------
// Kernel 2: W [K,N] fp32 -> WT [N,K] bf16
// ---------------------------------------------------------------------------
__global__ __launch_bounds__(256)
void transpose_cast_kernel(const float* __restrict__ W, u16* __restrict__ WT)
{
    __shared__ float tile[64][65];
    const int t = threadIdx.x;
    const int bx = blockIdx.x * 64, by = blockIdx.y * 64;
#pragma unroll
    for (int i = 0; i < 16; ++i) {
        int idx = i * 256 + t, r = idx >> 6, c = idx & 63;
        tile[r][c] = W[(size_t)(by + r) * DIM + bx + c];
    }
    __syncthreads();
#pragma unroll
    for (int i = 0; i < 16; ++i) {
        int idx = i * 256 + t, r = idx >> 6, c = idx & 63;
        WT[(size_t)(bx + r) * DIM + by + c] = f2bf(tile[c][r]);
    }
}

// ---------------------------------------------------------------------------
// Kernel 3: bf16 MFMA GEMM, 128x128 tile (m97 structure).
// MODE 0: batched LN'd q|k|v @ W_in -> FT (bf16 dim-major) + Fseq (q only)
// MODE 1: G @ W_out + b_out -> fp32 out
// ---------------------------------------------------------------------------
template <int MODE>
__global__ __launch_bounds__(256)
void mfma_gemm_kernel(const u16* __restrict__ A, const u16* __restrict__ BT,
                      const float* __restrict__ bias, float* __restrict__ C,
                      u16* __restrict__ FT, u16* __restrict__ Fseq)
{
    __shared__ u16 As[128 * 32];
    __shared__ u16 Bs[128 * 32];
    const int t = threadIdx.x, lane = t & 63, w = t >> 6;
    const int wr = w >> 1, wc = w & 1;
    const int r0 = blockIdx.x * 128, c0 = blockIdx.y * 128;
    const int cl = lane & 15, q = lane >> 4;

    f32x4 acc[4][4];
#pragma unroll
    for (int i = 0; i < 4; ++i)
#pragma unroll
        for (int j = 0; j < 4; ++j) acc[i][j] = (f32x4){0.f, 0.f, 0.f, 0.f};

    for (int k0 = 0; k0 < DIM; k0 += 32) {
#pragma unroll
        for (int i = 0; i < 2; ++i) {
            int idx = i * 256 + t;
            int row = idx >> 2, ch = idx & 3;
            gload16(A  + (size_t)(r0 + row) * DIM + k0 + ch * 8, As + idx * 8);
            gload16(BT + (size_t)(c0 + row) * DIM + k0 + ch * 8, Bs + idx * 8);
        }
        __syncthreads();
        bf16x8 af[4], bfr[4];
#pragma unroll
        for (int mi = 0; mi < 4; ++mi)
            af[mi] = *(const bf16x8*)(As + (wr * 64 + mi * 16 + cl) * 32 + q * 8);
#pragma unroll
        for (int ni = 0; ni < 4; ++ni)
            bfr[ni] = *(const bf16x8*)(Bs + (wc * 64 + ni * 16 + cl) * 32 + q * 8);
#pragma unroll
        for (int mi = 0; mi < 4; ++mi)
#pragma unroll
            for (int ni = 0; ni < 4; ++ni)
                acc[mi][ni] = __builtin_amdgcn_mfma_f32_16x16x32_bf16(af[mi], bfr[ni],
                                                                      acc[mi][ni], 0, 0, 0);
        __syncthreads();
    }
#pragma unroll
    for (int mi = 0; mi < 4; ++mi) {
        int row0 = r0 + wr * 64 + mi * 16 + q * 4;   // 4 consecutive rows
#pragma unroll
        for (int ni = 0; ni < 4; ++ni) {
            int col = c0 + wc * 64 + ni * 16 + cl;
            if (MODE == 1) {
                float bv = bias[col];
#pragma unroll
                for (int r = 0; r < 4; ++r)
                    C[(size_t)(row0 + r) * DIM + col] = acc[mi][ni][r] + bv;
            } else {
                union { u16 h[4]; ushort4 u; } h4;
#pragma unroll
                for (int r = 0; r < 4; ++r) h4.h[r] = f2bf(acc[mi][ni][r]);
                int tns = row0 >> 14, b = (row0 >> 8) & 63, n = row0 & 255;
                *(ushort4*)(FT + (((size_t)(tns * 64 + b) * 512 + col) * 256 + n)) = h4.u;
                if (row0 < NROWS) {   // q rows: seq-major copy for attention stage 2
#pragma unroll
                    for (int r = 0; r < 4; ++r)
                        Fseq[(size_t)(row0 + r) * DIM + col] = h4.h[r];
                }
            }
        }
    }
}

// ---------------------------------------------------------------------------
// Kernel 4: per-(hb, tns) stats via MFMA Gram.
//   ET (dim-major bf16) -> row norms, mu, G=E^T E, Gc = G - N mu mu^T
//   V = mean relu(1 - sqrt(diag/255 + eps)), C = (||cov||^2 - diag^2)/64
// ---------------------------------------------------------------------------
__global__ __launch_bounds__(256)
void stats_kernel(const u16* __restrict__ FT, float* __restrict__ norms,
                  float2* __restrict__ vc)
{
    __shared__ u16 ET[64 * 264];      // 64 dims x 256 n, stride 264 (528B = 16*33)
    __shared__ float mu[64];
    __shared__ float red[4][64];
    __shared__ float wr3[4][3];
    const int hb = blockIdx.x, tns = blockIdx.y, h = hb >> 6, b = hb & 63;
    const int t = threadIdx.x, lane = t & 63, w = t >> 6, cl = lane & 15, q = lane >> 4;
    const size_t Fb = ((size_t)(tns * 64 + b) * 512 + h * 64) * 256;

    // stage ET: 64 rows x 32 16B-chunks = 2048 chunks
#pragma unroll
    for (int i = 0; i < 8; ++i) {
        int idx = t + 256 * i;
        int row = idx >> 5, ch = idx & 31;
        *(bf16x8*)(ET + row * 264 + ch * 8) =
            *(const bf16x8*)(FT + Fb + (size_t)row * 256 + ch * 8);
    }
    __syncthreads();

    // row norms (n = t): strided u16 reads, 2 lanes/bank -> free
    {
        float s = 0.f;
#pragma unroll
        for (int d = 0; d < 64; ++d) {
            float x = (float)*(const __bf16*)(ET + d * 264 + t);
            s += x * x;
        }
        norms[((size_t)tns * HB + hb) * 256 + t] = sqrtf(s);
    }
    // column means
    {
        int d = t & 63, part = t >> 6;
        float s = 0.f;
#pragma unroll
        for (int i = 0; i < 8; ++i) {
            bf16x8 v8 = *(const bf16x8*)(ET + d * 264 + part * 64 + i * 8);
#pragma unroll
            for (int j = 0; j < 8; ++j) s += (float)v8[j];
        }
        red[part][d] = s;
    }
    __syncthreads();
    if (t < 64) mu[t] = (red[0][t] + red[1][t] + red[2][t] + red[3][t]) * (1.f / 256.f);
    __syncthreads();

    // Gram via MFMA: wave w -> rows [16w,16w+16), K = 256
    f32x4 g[4];
#pragma unroll
    for (int nj = 0; nj < 4; ++nj) g[nj] = (f32x4){0.f, 0.f, 0.f, 0.f};
#pragma unroll
    for (int ks = 0; ks < 8; ++ks) {
        bf16x8 af = *(const bf16x8*)(ET + (16 * w + cl) * 264 + ks * 32 + q * 8);
#pragma unroll
        for (int nj = 0; nj < 4; ++nj) {
            bf16x8 bfr = *(const bf16x8*)(ET + (16 * nj + cl) * 264 + ks * 32 + q * 8);
            g[nj] = __builtin_amdgcn_mfma_f32_16x16x32_bf16(af, bfr, g[nj], 0, 0, 0);
        }
    }
    float t2 = 0.f, d2 = 0.f, vs = 0.f;
#pragma unroll
    for (int nj = 0; nj < 4; ++nj) {
        int j = 16 * nj + cl;
        float mj = mu[j];
#pragma unroll
        for (int r = 0; r < 4; ++r) {
            int i = 16 * w + 4 * q + r;
            float gc = (g[nj][r] - 256.f * mu[i] * mj) * (1.f / 255.f);  // cov[i][j]
            float g2 = gc * gc;
            t2 += g2;
            if (i == j) {
                d2 += g2;
                float sig = sqrtf(gc + 1e-8f);
                vs += fmaxf(1.f - sig, 0.f);
            }
        }
    }
#pragma unroll
    for (int o = 32; o > 0; o >>= 1) {
        t2 += __shfl_xor(t2, o, 64);
        d2 += __shfl_xor(d2, o, 64);
        vs += __shfl_xor(vs, o, 64);
    }
    if (lane == 0) { wr3[w][0] = t2; wr3[w][1] = d2; wr3[w][2] = vs; }
    __syncthreads();
    if (t == 0) {
        float T = 0.f, D = 0.f, V = 0.f;
        for (int i = 0; i < 4; ++i) { T += wr3[i][0]; D += wr3[i][1]; V += wr3[i][2]; }
        vc[(size_t)tns * HB + hb] = make_float2(V * (1.f / 64.f), (T - D) * (1.f / 64.f));
    }
}

// ---------------------------------------------------------------------------
// Kernel 5: chunk-combine
// ---------------------------------------------------------------------------
__global__ void combine_kernel(const float2* __restrict__ vc, const float* __restrict__ cov_logit,
                               const float* __restrict__ var_logit, float* __restrict__ s_out)
{
    int hb = threadIdx.x + blockIdx.x * blockDim.x;
    if (hb >= HB) return;
    int base = hb & ~7;
    float vq = 0, cq = 0, vk = 0, ck = 0;
#pragma unroll
    for (int m = 0; m < 8; ++m) {
        float2 a = vc[base + m];      vq += a.x; cq += a.y;
        float2 b = vc[HB + base + m]; vk += b.x; ck += b.y;
    }
    float cw = sigmoidf_(*cov_logit), vw = sigmoidf_(*var_logit);
    s_out[hb] = (cw * cq * ck + vw * vq * vk) * (1.f / 64.f);
}

// ---------------------------------------------------------------------------
// Kernel 6: attention per (h,b) via MFMA.
//   Stage 1: M = khat^T fv (64x64, K=256, khat scaled on LDS load), sumv free.
//   Stage 2: O = qraw @ M, 1/||q|| folded into epilogue; coalesced bf16 store.
// ---------------------------------------------------------------------------
__global__ __launch_bounds__(256)
void attn_kernel(const u16* __restrict__ FT, const u16* __restrict__ Fseq,
                 const float* __restrict__ norms, const float* __restrict__ s_arr,
                 const float* __restrict__ cov_logit, const float* __restrict__ var_logit,
                 u16* __restrict__ G)
{
    __shared__ u16 pool[256 * 72];        // KT[64][136]+VT[64][136] | Os[256][72]
    __shared__ u16 MT[64 * 72];           // M^T bf16, stride 72 (144B = 16*9)
    __shared__ float invq[256], invk[256], sv[64];
    const int hb = blockIdx.x, h = hb >> 6, b = hb & 63;
    const int t = threadIdx.x, lane = t & 63, w = t >> 6, cl = lane & 15, q = lane >> 4;
    u16* KT = pool;
    u16* VT = pool + 64 * 136;

    invq[t] = 1.f / norms[((size_t)0 * HB + hb) * 256 + t];
    invk[t] = 1.f / norms[((size_t)1 * HB + hb) * 256 + t];
    __syncthreads();

    const size_t FTk = ((size_t)(1 * 64 + b) * 512 + h * 64) * 256;
    const size_t FTv = ((size_t)(2 * 64 + b) * 512 + h * 64) * 256;
    f32x4 acc1[4];
#pragma unroll
    for (int nj = 0; nj < 4; ++nj) acc1[nj] = (f32x4){0.f, 0.f, 0.f, 0.f};
    float sp[4] = {0.f, 0.f, 0.f, 0.f};

    for (int c = 0; c < 2; ++c) {          // n-chunks of 128
#pragma unroll
        for (int i = 0; i < 4; ++i) {
            int idx = t + 256 * i;          // 1024 8-elem chunks: row=idx>>4, ch=idx&15
            int row = idx >> 4, ch = idx & 15;
            int n0 = c * 128 + ch * 8;
            bf16x8 kv = *(const bf16x8*)(FT + FTk + (size_t)row * 256 + n0);
            bf16x8 vv = *(const bf16x8*)(FT + FTv + (size_t)row * 256 + n0);
            bf16x8 ksc;
#pragma unroll
            for (int j = 0; j < 8; ++j) ksc[j] = (__bf16)((float)kv[j] * invk[n0 + j]);
            *(bf16x8*)(KT + row * 136 + ch * 8) = ksc;
            *(bf16x8*)(VT + row * 136 + ch * 8) = vv;
        }
        __syncthreads();
#pragma unroll
        for (int ks = 0; ks < 4; ++ks) {
            bf16x8 af = *(const bf16x8*)(KT + (16 * w + cl) * 136 + ks * 32 + q * 8);
#pragma unroll
            for (int nj = 0; nj < 4; ++nj) {
                bf16x8 bfr = *(const bf16x8*)(VT + (16 * nj + cl) * 136 + ks * 32 + q * 8);
                if (w == 0) {
                    float s = 0.f;
#pragma unroll
                    for (int j = 0; j < 8; ++j) s += (float)bfr[j];
                    sp[nj] += s;
                }
                acc1[nj] = __builtin_amdgcn_mfma_f32_16x16x32_bf16(af, bfr, acc1[nj], 0, 0, 0);
            }
        }
        __syncthreads();
    }
    if (w == 0) {
#pragma unroll
        for (int nj = 0; nj < 4; ++nj) {
            float s = sp[nj];
            s += __shfl_xor(s, 16, 64);
            s += __shfl_xor(s, 32, 64);
            if (q == 0) sv[16 * nj + cl] = s;
        }
    }
    // M^T[j][i] = M[i][j]; i = 16w + 4q + r, j = 16nj + cl
#pragma unroll
    for (int nj = 0; nj < 4; ++nj)
#pragma unroll
        for (int r = 0; r < 4; ++r)
            MT[(16 * nj + cl) * 72 + 16 * w + 4 * q + r] = f2bf(acc1[nj][r]);
    __syncthreads();

    // stage 2: O[n][j] = sum_i q[n][i] M[i][j]; wave w -> rows [64w, 64w+64)
    const float cw = sigmoidf_(*cov_logit), vw = sigmoidf_(*var_logit);
    const float cosw = 1.f - cw - vw;
    const float s_hb = s_arr[hb];
    f32x4 acc2[4][4];
#pragma unroll
    for (int mi = 0; mi < 4; ++mi)
#pragma unroll
        for (int nj = 0; nj < 4; ++nj) acc2[mi][nj] = (f32x4){0.f, 0.f, 0.f, 0.f};
    const size_t Fq = (size_t)(b * 256) * DIM + h * 64;
#pragma unroll
    for (int ks2 = 0; ks2 < 2; ++ks2) {
        bf16x8 bfm[4];
#pragma unroll
        for (int nj = 0; nj < 4; ++nj)
            bfm[nj] = *(const bf16x8*)(MT + (16 * nj + cl) * 72 + ks2 * 32 + q * 8);
#pragma unroll
        for (int mi = 0; mi < 4; ++mi) {
            bf16x8 aq = *(const bf16x8*)(Fseq + Fq +
                         (size_t)(64 * w + 16 * mi + cl) * DIM + ks2 * 32 + q * 8);
#pragma unroll
            for (int nj = 0; nj < 4; ++nj)
                acc2[mi][nj] = __builtin_amdgcn_mfma_f32_16x16x32_bf16(aq, bfm[nj],
                                                                       acc2[mi][nj], 0, 0, 0);
        }
    }
    __syncthreads();   // pool -> Os reuse
    u16* Os = pool;    // [256][72]
#pragma unroll
    for (int mi = 0; mi < 4; ++mi) {
        int nbase = 64 * w + 16 * mi + 4 * q;
#pragma unroll
        for (int nj = 0; nj < 4; ++nj) {
            int j = 16 * nj + cl;
            float svj = sv[j];
#pragma unroll
            for (int r = 0; r < 4; ++r) {
                float o = cosw * acc2[mi][nj][r] * invq[nbase + r] + s_hb * svj;
                Os[(nbase + r) * 72 + j] = f2bf(o);
            }
        }
    }
    __syncthreads();
#pragma unroll
    for (int i = 0; i < 8; ++i) {
        int cidx = t + 256 * i;               // 2048 16B chunks: row=cidx>>3, ch=cidx&7
        int row = cidx >> 3, ch = cidx & 7;
        *(uint4*)(G + (size_t)(b * 256 + row) * DIM + h * 64 + ch * 8) =
            *(const uint4*)(Os + row * 72 + ch * 8);
    }
}

// ---------------------------------------------------------------------------
extern "C" void kernel_launch(void* const* d_in, const int* in_sizes, int n_in,
                              void* d_out, int out_size, void* d_ws, size_t ws_size,
                              hipStream_t stream)
{
    const float* q         = (const float*)d_in[0];
    const float* k         = (const float*)d_in[1];
    const float* v         = (const float*)d_in[2];
    const float* ln_g      = (const float*)d_in[3];
    const float* ln_b      = (const float*)d_in[4];
    const float* W_in      = (const float*)d_in[5];
    const float* W_out     = (const float*)d_in[6];
    const float* b_out     = (const float*)d_in[7];
    const float* cov_logit = (const float*)d_in[8];
    const float* var_logit = (const float*)d_in[9];
    float* out = (float*)d_out;

    // workspace (119,547,904 B total — same footprint as round 2):
    char* base = (char*)d_ws;
    u16*    Abf   = (u16*)base;                                   // 50,331,648  (LN'd q|k|v)
    u16*    WT    = (u16*)(base + 50331648);                      //  1,048,576  (W_in^T | W_out^T)
    u16*    FT    = (u16*)(base + 51380224);                      // 50,331,648  (dim-major F)
    u16*    Fseq  = (u16*)(base + 101711872);                     // 16,777,216  (seq-major f_q)
    float*  norms = (float*)(base + 118489088);                   //  1,048,576
    float2* vc    = (float2*)(base + 119537664);                  //      8,192
    float*  s_arr = (float*)(base + 119545856);                   //      2,048
    u16*    Gb    = Abf;                                          // alias: Abf dead after GEMM

    transpose_cast_kernel<<<dim3(8, 8), 256, 0, stream>>>(W_in, WT);
    transpose_cast_kernel<<<dim3(8, 8), 256, 0, stream>>>(W_out, WT + 512 * 512);

    const float* in3[3] = {q, k, v};
    for (int tns = 0; tns < 3; ++tns)
        ln_cast_kernel<<<dim3(NROWS / 4), 256, 0, stream>>>(in3[tns], ln_g, ln_b,
                                                            Abf + (size_t)tns * NROWS * DIM);
    mfma_gemm_kernel<0><<<dim3(3 * NROWS / 128, 4), 256, 0, stream>>>(
        Abf, WT, nullptr, nullptr, FT, Fseq);

    stats_kernel<<<dim3(HB, 2), 256, 0, stream>>>(FT, norms, vc);
    combine_kernel<<<dim3(1), 512, 0, stream>>>(vc, cov_logit, var_logit, s_arr);
    attn_kernel<<<dim3(HB), 256, 0, stream>>>(FT, Fseq, norms, s_arr,
                                              cov_logit, var_logit, Gb);
    mfma_gemm_kernel<1><<<dim3(NROWS / 128, 4), 256, 0, stream>>>(
        Gb, WT + 512 * 512, b_out, out, nullptr, nullptr);
}